// Round 1
// baseline (351.206 us; speedup 1.0000x reference)
//
#include <hip/hip_runtime.h>

#define TH 32
#define TW 64
#define PW 88   // LDS row pitch in floats (TW + 24), multiple of 4 for float4

__device__ __forceinline__ int symidx(int t, int n) {
    // symmetric extension (edge included), single reflection is enough (m<=9, n=256)
    t = (t < 0) ? (-1 - t) : t;
    return (t >= n) ? (2 * n - 1 - t) : t;
}

// column filter of Yl with 13 taps, scattered accumulation
__device__ __forceinline__ void col13_yl(
    float (&acc)[TH], const float* __restrict__ ylp,
    const float (&taps)[13], int r0, int cc)
{
    #pragma unroll
    for (int pi = 0; pi < TH + 12; ++pi) {
        int rr = symidx(r0 - 6 + pi, 256);
        float v = ylp[rr * 256 + cc];
        #pragma unroll
        for (int j = 0; j < 13; ++j) {
            int ro = pi + j - 12;
            if (ro >= 0 && ro < TH) acc[ro] = fmaf(taps[j], v, acc[ro]);
        }
    }
}

// column filter (13 taps) of a c2q composite (bands bA,bB), scattered accumulation
__device__ __forceinline__ void col13_c2q(
    float (&acc)[TH], const float* __restrict__ yhr, const float* __restrict__ yhi,
    int bA, int bB, const float (&taps)[13], int r0, int cc)
{
    const int cp = cc & 1;
    const int j2 = cc >> 1;
    const float IS2 = 0.70710678118654752f;
    #pragma unroll
    for (int pi = 0; pi < TH + 12; ++pi) {
        int rr = symidx(r0 - 6 + pi, 256);
        int rp = rr & 1;
        int i2 = rr >> 1;
        const float* base = (((rp ^ cp) != 0) ? yhi : yhr) + (i2 * 128 + j2);
        float A  = base[bA * 16384];
        float Bv = base[bB * 16384];
        // quad signs: (0,0):+A+B  (0,1):+A+B  (1,0):+A-B  (1,1):-A+B
        float vA = (rp & cp)       ? -A  : A;
        float vB = (rp & (cp ^ 1)) ? -Bv : Bv;
        float v = (vA + vB) * IS2;
        #pragma unroll
        for (int j = 0; j < 13; ++j) {
            int ro = pi + j - 12;
            if (ro >= 0 && ro < TH) acc[ro] = fmaf(taps[j], v, acc[ro]);
        }
    }
}

// column filter (19 taps) of the lh composite (bands 0,5), scattered accumulation
__device__ __forceinline__ void col19_c2q(
    float (&acc)[TH], const float* __restrict__ yhr, const float* __restrict__ yhi,
    const float (&taps)[19], int r0, int cc)
{
    const int bA = 0, bB = 5;
    const int cp = cc & 1;
    const int j2 = cc >> 1;
    const float IS2 = 0.70710678118654752f;
    #pragma unroll
    for (int pi = 0; pi < TH + 18; ++pi) {
        int rr = symidx(r0 - 9 + pi, 256);
        int rp = rr & 1;
        int i2 = rr >> 1;
        const float* base = (((rp ^ cp) != 0) ? yhi : yhr) + (i2 * 128 + j2);
        float A  = base[bA * 16384];
        float Bv = base[bB * 16384];
        float vA = (rp & cp)       ? -A  : A;
        float vB = (rp & (cp ^ 1)) ? -Bv : Bv;
        float v = (vA + vB) * IS2;
        #pragma unroll
        for (int j = 0; j < 19; ++j) {
            int ro = pi + j - 18;
            if (ro >= 0 && ro < TH) acc[ro] = fmaf(taps[j], v, acc[ro]);
        }
    }
}

extern "C" __global__ __launch_bounds__(512) void dtcwt_inv(
    const float* __restrict__ Yl, const float* __restrict__ Yhr,
    const float* __restrict__ Yhi,
    const float* __restrict__ g0, const float* __restrict__ g1,
    const float* __restrict__ g2, float* __restrict__ out)
{
    // sT[0]=t1a=col_g0(Yl), sT[1]=t1b=col_g1(lh), sT[2]=t2=col_g0(hl), sT[3]=t3=col_g2(hh)
    // array col index ti corresponds to (extended) image col c0 + ti - 12
    __shared__ __align__(16) float sT[4][TH][PW];

    const int tid = threadIdx.x;
    const int plane = blockIdx.z;              // b*64 + c
    const int r0 = blockIdx.y * TH;
    const int c0 = blockIdx.x * TW;

    const float* ylp = Yl  + (size_t)plane * 65536;
    const float* yhr = Yhr + (size_t)plane * 6 * 16384;
    const float* yhi = Yhi + (size_t)plane * 6 * 16384;

    float G0[13], G1[19], G2[13];
    #pragma unroll
    for (int j = 0; j < 13; ++j) G0[j] = g0[j];
    #pragma unroll
    for (int j = 0; j < 19; ++j) G1[j] = g1[j];
    #pragma unroll
    for (int j = 0; j < 13; ++j) G2[j] = g2[j];

    // ---------------- stage 1: column filters into LDS ----------------
    const int role = tid >> 7;   // wave-pair roles: 0:t1a 1:t1b 2:t2 3:t3
    const int lr   = tid & 127;

    float acc[TH];
    #pragma unroll
    for (int i = 0; i < TH; ++i) acc[i] = 0.0f;

    int ti = -1;
    if (role == 0) {
        if (lr < 76) {           // t1 needs cols idx [6, 82)
            ti = lr + 6;
            int cc = symidx(c0 + ti - 12, 256);
            col13_yl(acc, ylp, G0, r0, cc);
        }
    } else if (role == 1) {
        if (lr < 76) {
            ti = lr + 6;
            int cc = symidx(c0 + ti - 12, 256);
            col19_c2q(acc, yhr, yhi, G1, r0, cc);
        }
    } else if (role == 2) {
        if (lr < 82) {           // t2 row-filtered by g1 -> cols idx [3, 85)
            ti = lr + 3;
            int cc = symidx(c0 + ti - 12, 256);
            col13_c2q(acc, yhr, yhi, 2, 3, G0, r0, cc);
        }
    } else {
        if (lr < 76) {
            ti = lr + 6;
            int cc = symidx(c0 + ti - 12, 256);
            col13_c2q(acc, yhr, yhi, 1, 4, G2, r0, cc);
        }
    }
    if (ti >= 0) {
        #pragma unroll
        for (int ro = 0; ro < TH; ++ro) sT[role][ro][ti] = acc[ro];
    }
    __syncthreads();

    // ---------------- stage 2: row filters from LDS -> 4 outputs/thread ----------------
    const int cg = tid & 15;     // column group (4 consecutive output cols)
    const int r  = tid >> 4;     // 0..31
    const int cb = 4 * cg;

    float w1[20];                // t1a+t1b, abs idx [cb+4, cb+24)
    #pragma unroll
    for (int k = 0; k < 5; ++k) {
        float4 a = *(const float4*)&sT[0][r][cb + 4 + 4 * k];
        float4 b = *(const float4*)&sT[1][r][cb + 4 + 4 * k];
        w1[4*k+0] = a.x + b.x; w1[4*k+1] = a.y + b.y;
        w1[4*k+2] = a.z + b.z; w1[4*k+3] = a.w + b.w;
    }
    float w2[28];                // t2, abs idx [cb, cb+28)
    #pragma unroll
    for (int k = 0; k < 7; ++k) {
        float4 a = *(const float4*)&sT[2][r][cb + 4 * k];
        w2[4*k+0] = a.x; w2[4*k+1] = a.y; w2[4*k+2] = a.z; w2[4*k+3] = a.w;
    }
    float w3[20];                // t3, abs idx [cb+4, cb+24)
    #pragma unroll
    for (int k = 0; k < 5; ++k) {
        float4 a = *(const float4*)&sT[3][r][cb + 4 + 4 * k];
        w3[4*k+0] = a.x; w3[4*k+1] = a.y; w3[4*k+2] = a.z; w3[4*k+3] = a.w;
    }

    float4 res;
    float* rp = (float*)&res;
    #pragma unroll
    for (int q = 0; q < 4; ++q) {
        float s = 0.0f;
        #pragma unroll
        for (int j = 0; j < 13; ++j) s = fmaf(G0[j], w1[q + 14 - j], s);  // abs cb+q+18-j
        #pragma unroll
        for (int j = 0; j < 19; ++j) s = fmaf(G1[j], w2[q + 21 - j], s);  // abs cb+q+21-j
        #pragma unroll
        for (int j = 0; j < 13; ++j) s = fmaf(G2[j], w3[q + 14 - j], s);  // abs cb+q+18-j
        rp[q] = s;
    }
    *(float4*)&out[(size_t)plane * 65536 + (size_t)(r0 + r) * 256 + (c0 + cb)] = res;
}

extern "C" void kernel_launch(void* const* d_in, const int* in_sizes, int n_in,
                              void* d_out, int out_size, void* d_ws, size_t ws_size,
                              hipStream_t stream) {
    const float* Yl  = (const float*)d_in[0];
    const float* Yhr = (const float*)d_in[1];
    const float* Yhi = (const float*)d_in[2];
    const float* g0  = (const float*)d_in[3];
    const float* g1  = (const float*)d_in[4];
    const float* g2  = (const float*)d_in[5];
    float* out = (float*)d_out;

    dim3 grid(256 / TW, 256 / TH, 8 * 64);   // (4, 8, 512)
    dim3 block(512, 1, 1);
    dtcwt_inv<<<grid, block, 0, stream>>>(Yl, Yhr, Yhi, g0, g1, g2, out);
}